// Round 1
// baseline (302.679 us; speedup 1.0000x reference)
//
#include <hip/hip_runtime.h>
#include <hip/hip_fp16.h>
#include <stdint.h>

typedef int i32x4 __attribute__((ext_vector_type(4)));

#define TM 128
#define TN 128
#define BK 64

__device__ __forceinline__ void gload_lds16(const void* g, void* l) {
  __builtin_amdgcn_global_load_lds(
      (const __attribute__((address_space(1))) unsigned int*)g,
      (__attribute__((address_space(3))) unsigned int*)l, 16, 0, 0);
}

// ---------------- quantize x: fp32(fp16 values) -> int8, 16 elems/thread ----
__global__ __launch_bounds__(256) void quant_x_kernel(
    const float* __restrict__ x, const float* __restrict__ deltap,
    const float* __restrict__ zpp, int8_t* __restrict__ q, int n16) {
  int i = blockIdx.x * blockDim.x + threadIdx.x;
  if (i >= n16) return;
  const float delta = deltap[0];
  const float zp = zpp[0];
  const float4* src = (const float4*)x + (size_t)i * 4;
  int packed[4];
#pragma unroll
  for (int g = 0; g < 4; ++g) {
    float4 v = src[g];
    float f0 = fminf(127.f, fmaxf(-128.f, rintf(v.x / delta + zp)));
    float f1 = fminf(127.f, fmaxf(-128.f, rintf(v.y / delta + zp)));
    float f2 = fminf(127.f, fmaxf(-128.f, rintf(v.z / delta + zp)));
    float f3 = fminf(127.f, fmaxf(-128.f, rintf(v.w / delta + zp)));
    int q0 = (int)f0 & 255, q1 = (int)f1 & 255, q2 = (int)f2 & 255, q3 = (int)f3 & 255;
    packed[g] = q0 | (q1 << 8) | (q2 << 16) | (q3 << 24);
  }
  ((int4*)q)[i] = make_int4(packed[0], packed[1], packed[2], packed[3]);
}

// ---------------- pack W: int32 -> int8, 16 elems/thread --------------------
__global__ __launch_bounds__(256) void pack_w_kernel(
    const int* __restrict__ w, int8_t* __restrict__ wp, int n16) {
  int i = blockIdx.x * blockDim.x + threadIdx.x;
  if (i >= n16) return;
  const int4* src = (const int4*)w + (size_t)i * 4;
  int packed[4];
#pragma unroll
  for (int g = 0; g < 4; ++g) {
    int4 v = src[g];
    packed[g] = (v.x & 255) | ((v.y & 255) << 8) | ((v.z & 255) << 16) | ((v.w & 255) << 24);
  }
  ((int4*)wp)[i] = make_int4(packed[0], packed[1], packed[2], packed[3]);
}

// ---------------- int8 GEMM: C[M,N] = q[M,K] . W[N,K]^T + fused dequant -----
// m97 structure: 128x128 tile, 4 waves (2x2), 4x4 16x16 frags/wave, BK=64,
// global_load_lds width=16 staging, single LDS buffer, 2 barriers per K-step.
__global__ __launch_bounds__(256) void gemm_i8_kernel(
    const int8_t* __restrict__ Aq, const int8_t* __restrict__ Bw,
    const float* __restrict__ atwd, const float* __restrict__ zpws,
    const float* __restrict__ bias, float* __restrict__ out,
    int Mc, int Nc, int Kc) {
  __shared__ int8_t sA[TM * BK];
  __shared__ int8_t sB[TN * BK];
  const int bm = blockIdx.y;
  const int bn = blockIdx.x;
  const int t = threadIdx.x;
  const int lane = t & 63;
  const int wave = t >> 6;
  const int wr = wave >> 1;          // wave row (0..1), owns 64 rows
  const int wc = wave & 1;           // wave col (0..1), owns 64 cols
  const int fr = lane & 15;          // fragment row/col index
  const int kc = lane >> 4;          // k-chunk 0..3 (16 bytes each)
  const size_t K = (size_t)Kc;

  i32x4 acc[4][4] = {};

  // staging: thread t loads 16B; LDS dest linear = base + t*16 (wave-uniform
  // base + lane*16 as required by global_load_lds)
  const int srow = t >> 2;           // 0..63
  const int scol = (t & 3) << 4;     // 0,16,32,48
  const int8_t* gA = Aq + (size_t)(bm * TM + srow) * K + scol;
  const int8_t* gB = Bw + (size_t)(bn * TN + srow) * K + scol;
  int8_t* lA = &sA[t * 16];
  int8_t* lB = &sB[t * 16];
  const size_t rowoff = (size_t)64 * K;

  for (int k0 = 0; k0 < Kc; k0 += BK) {
    gload_lds16(gA + k0, lA);
    gload_lds16(gA + k0 + rowoff, lA + 64 * BK);
    gload_lds16(gB + k0, lB);
    gload_lds16(gB + k0 + rowoff, lB + 64 * BK);
    __syncthreads();   // compiler emits vmcnt(0) drain before barrier

    i32x4 af[4], bf[4];
#pragma unroll
    for (int i = 0; i < 4; ++i)
      af[i] = *(const i32x4*)&sA[(wr * 64 + i * 16 + fr) * BK + kc * 16];
#pragma unroll
    for (int j = 0; j < 4; ++j)
      bf[j] = *(const i32x4*)&sB[(wc * 64 + j * 16 + fr) * BK + kc * 16];

#pragma unroll
    for (int i = 0; i < 4; ++i)
#pragma unroll
      for (int j = 0; j < 4; ++j)
        acc[i][j] = __builtin_amdgcn_mfma_i32_16x16x64_i8(af[i], bf[j], acc[i][j], 0, 0, 0);

    __syncthreads();   // protect LDS before next stage
  }

  // epilogue: C/D layout col=lane&15, row=(lane>>4)*4+reg (dtype-independent)
  const int r4 = (lane >> 4) << 2;
#pragma unroll
  for (int j = 0; j < 4; ++j) {
    const int cn = bn * TN + wc * 64 + j * 16 + fr;
    const float aw = atwd[cn];
    const float zs = zpws[cn];
    const float bs = bias[cn];
#pragma unroll
    for (int i = 0; i < 4; ++i) {
      const size_t rbase = (size_t)(bm * TM + wr * 64 + i * 16 + r4) * (size_t)Nc;
#pragma unroll
      for (int r = 0; r < 4; ++r) {
        float v = (float)acc[i][j][r] * aw - zs + bs;
        v = __half2float(__float2half(v));  // match fp16 output rounding
        out[rbase + (size_t)r * Nc + cn] = v;
      }
    }
  }
}

extern "C" void kernel_launch(void* const* d_in, const int* in_sizes, int n_in,
                              void* d_out, int out_size, void* d_ws, size_t ws_size,
                              hipStream_t stream) {
  const float* x         = (const float*)d_in[0];
  const float* act_delta = (const float*)d_in[1];
  const float* act_zp    = (const float*)d_in[2];
  const float* zpws      = (const float*)d_in[3];
  const float* atwd      = (const float*)d_in[4];
  const float* bias      = (const float*)d_in[5];
  const int*   w32       = (const int*)d_in[6];
  float* out = (float*)d_out;

  const int N = in_sizes[5];
  const int K = in_sizes[6] / N;
  const int M = in_sizes[0] / K;

  int8_t* q  = (int8_t*)d_ws;               // M*K bytes
  int8_t* wp = q + (size_t)M * K;           // N*K bytes

  {
    int n16 = (M * K) / 16;
    quant_x_kernel<<<(n16 + 255) / 256, 256, 0, stream>>>(x, act_delta, act_zp, q, n16);
  }
  {
    int n16 = (N * K) / 16;
    pack_w_kernel<<<(n16 + 255) / 256, 256, 0, stream>>>(w32, wp, n16);
  }
  {
    dim3 grid(N / TN, M / TM);
    gemm_i8_kernel<<<grid, 256, 0, stream>>>(q, wp, atwd, zpws, bias, out, M, N, K);
  }
}

// Round 2
// 271.067 us; speedup vs baseline: 1.1166x; 1.1166x over previous
//
#include <hip/hip_runtime.h>
#include <hip/hip_fp16.h>
#include <stdint.h>

typedef int i32x4 __attribute__((ext_vector_type(4)));

#define BM 256
#define BN 256
#define BKB 64            // K-bytes (= int8 elems) per tile
#define NSLOT 4
#define SLOT_BYTES 32768  // A 16KB + B 16KB per slot
#define THREADS 512

__device__ __forceinline__ void gload_lds16(const void* g, void* l) {
  __builtin_amdgcn_global_load_lds(
      (const __attribute__((address_space(1))) unsigned int*)g,
      (__attribute__((address_space(3))) unsigned int*)l, 16, 0, 0);
}

// ---------------- quantize x: fp32(fp16 values) -> int8, 16 elems/thread ----
__global__ __launch_bounds__(256) void quant_x_kernel(
    const float* __restrict__ x, const float* __restrict__ deltap,
    const float* __restrict__ zpp, int8_t* __restrict__ q, int n16) {
  int i = blockIdx.x * blockDim.x + threadIdx.x;
  if (i >= n16) return;
  const float rdelta = 1.0f / deltap[0];
  const float zp = zpp[0];
  const float4* src = (const float4*)x + (size_t)i * 4;
  int packed[4];
#pragma unroll
  for (int g = 0; g < 4; ++g) {
    float4 v = src[g];
    float f0 = fminf(127.f, fmaxf(-128.f, rintf(fmaf(v.x, rdelta, zp))));
    float f1 = fminf(127.f, fmaxf(-128.f, rintf(fmaf(v.y, rdelta, zp))));
    float f2 = fminf(127.f, fmaxf(-128.f, rintf(fmaf(v.z, rdelta, zp))));
    float f3 = fminf(127.f, fmaxf(-128.f, rintf(fmaf(v.w, rdelta, zp))));
    int q0 = (int)f0 & 255, q1 = (int)f1 & 255, q2 = (int)f2 & 255, q3 = (int)f3 & 255;
    packed[g] = q0 | (q1 << 8) | (q2 << 16) | (q3 << 24);
  }
  ((int4*)q)[i] = make_int4(packed[0], packed[1], packed[2], packed[3]);
}

// ---------------- pack W: int32 -> int8, 16 elems/thread --------------------
__global__ __launch_bounds__(256) void pack_w_kernel(
    const int* __restrict__ w, int8_t* __restrict__ wp, int n16) {
  int i = blockIdx.x * blockDim.x + threadIdx.x;
  if (i >= n16) return;
  const int4* src = (const int4*)w + (size_t)i * 4;
  int packed[4];
#pragma unroll
  for (int g = 0; g < 4; ++g) {
    int4 v = src[g];
    packed[g] = (v.x & 255) | ((v.y & 255) << 8) | ((v.z & 255) << 16) | ((v.w & 255) << 24);
  }
  ((int4*)wp)[i] = make_int4(packed[0], packed[1], packed[2], packed[3]);
}

// ---------------- int8 GEMM, 256x256 tile, counted-vmcnt phase pipeline -----
// 8 waves (2M x 4N), per-wave 128x64 out, acc[8][4] i32x4.
// LDS: 4-slot rotation (4 x 32KB), prefetch depth 3, vmcnt(8) steady state.
// T2 swizzle: storage chunk = logical chunk ^ ((row>>1)&3); linear LDS dest,
// inverse-swizzled global source (rule #21), swizzled ds_read.
__global__ __launch_bounds__(THREADS, 2) void gemm_i8_kernel(
    const int8_t* __restrict__ Aq, const int8_t* __restrict__ Bw,
    const float* __restrict__ atwd, const float* __restrict__ zpws,
    const float* __restrict__ bias, float* __restrict__ out,
    int Mc, int Nc, int Kc) {
  __shared__ int8_t lds[NSLOT * SLOT_BYTES];

  // ---- block id: T1 bijective XCD swizzle (nwg multiple of 8 here) ----
  const int nwg = gridDim.x;
  int bid = blockIdx.x;
  if ((nwg & 7) == 0) bid = (bid & 7) * (nwg >> 3) + (bid >> 3);
  const int nbn = Nc / BN;
  const int bm = bid / nbn;
  const int bn = bid % nbn;

  const int tid = threadIdx.x;
  const size_t K = (size_t)Kc;
  const int NT = Kc / BKB;

  // ---- staging geometry: sweep = 512 thr x 16B = 8KB = 128 rows x 64B ----
  const int srow = tid >> 2;                        // 0..127
  const int c_log = (tid & 3) ^ ((tid >> 3) & 3);   // inverse-swizzled source chunk
  const int8_t* gA = Aq + ((size_t)(bm * BM + srow)) * K + c_log * 16;
  const int8_t* gB = Bw + ((size_t)(bn * BN + srow)) * K + c_log * 16;
  const size_t half_off = (size_t)128 * K;
  int8_t* ldst = &lds[tid * 16];                    // linear in-slot dest

  auto stageA = [&](int t, int h) {
    gload_lds16(gA + (size_t)h * half_off + (size_t)t * BKB,
                ldst + (t & 3) * SLOT_BYTES + h * 8192);
  };
  auto stageB = [&](int t, int h) {
    gload_lds16(gB + (size_t)h * half_off + (size_t)t * BKB,
                ldst + (t & 3) * SLOT_BYTES + 16384 + h * 8192);
  };

  // ---- fragment geometry ----
  const int lane = tid & 63;
  const int wave = tid >> 6;
  const int wr = wave >> 2;          // 0..1 -> 128 rows
  const int wc = wave & 3;           // 0..3 -> 64 cols
  const int fr = lane & 15;
  const int kc = lane >> 4;
  const int coff = (kc ^ ((fr >> 1) & 3)) << 4;   // swizzled ds_read chunk
  const int aRow = wr * 128 + fr;
  const int bRow = wc * 64 + fr;

  i32x4 acc[8][4] = {};

  // ---- prologue: stage tiles 0..2, wait tile 0 landed ----
  stageA(0, 0); stageA(0, 1); stageB(0, 0); stageB(0, 1);
  if (NT > 1) { stageA(1, 0); stageA(1, 1); stageB(1, 0); stageB(1, 1); }
  if (NT > 2) { stageA(2, 0); stageA(2, 1); stageB(2, 0); stageB(2, 1); }
  if (NT >= 3) asm volatile("s_waitcnt vmcnt(8)" ::: "memory");
  else         asm volatile("s_waitcnt vmcnt(0)" ::: "memory");
  __builtin_amdgcn_s_barrier();

  for (int t = 0; t < NT; ++t) {
    const int8_t* sA = &lds[(t & 3) * SLOT_BYTES];
    const int8_t* sB = sA + 16384;
    const bool pf = (t + 3 < NT);
    i32x4 bfr[4], afr[4];

    // ---- phase 0: B frags + A frags (mh=0) | stage A of tile t+3 ----
#pragma unroll
    for (int j = 0; j < 4; ++j)
      bfr[j] = *(const i32x4*)&sB[(bRow + j * 16) * 64 + coff];
#pragma unroll
    for (int i = 0; i < 4; ++i)
      afr[i] = *(const i32x4*)&sA[(aRow + i * 16) * 64 + coff];
    if (pf) { stageA(t + 3, 0); stageA(t + 3, 1); }
    __builtin_amdgcn_s_barrier();
    asm volatile("s_waitcnt lgkmcnt(0)" ::: "memory");
    __builtin_amdgcn_s_setprio(1);
#pragma unroll
    for (int i = 0; i < 4; ++i)
#pragma unroll
      for (int j = 0; j < 4; ++j)
        acc[i][j] = __builtin_amdgcn_mfma_i32_16x16x64_i8(afr[i], bfr[j], acc[i][j], 0, 0, 0);
    __builtin_amdgcn_s_setprio(0);
    __builtin_amdgcn_s_barrier();

    // ---- phase 1: A frags (mh=1) | stage B of tile t+3 ----
#pragma unroll
    for (int i = 0; i < 4; ++i)
      afr[i] = *(const i32x4*)&sA[(aRow + 64 + i * 16) * 64 + coff];
    if (pf) { stageB(t + 3, 0); stageB(t + 3, 1); }
    __builtin_amdgcn_s_barrier();
    asm volatile("s_waitcnt lgkmcnt(0)" ::: "memory");
    __builtin_amdgcn_s_setprio(1);
#pragma unroll
    for (int i = 0; i < 4; ++i)
#pragma unroll
      for (int j = 0; j < 4; ++j)
        acc[4 + i][j] = __builtin_amdgcn_mfma_i32_16x16x64_i8(afr[i], bfr[j], acc[4 + i][j], 0, 0, 0);
    __builtin_amdgcn_s_setprio(0);
    // counted wait: tile t+1 must be landed before next iteration's ds_reads;
    // barrier after the wait makes it hold across ALL waves.
    if (t < NT - 3)       asm volatile("s_waitcnt vmcnt(8)" ::: "memory");
    else if (t == NT - 3) asm volatile("s_waitcnt vmcnt(4)" ::: "memory");
    else if (t == NT - 2) asm volatile("s_waitcnt vmcnt(0)" ::: "memory");
    __builtin_amdgcn_s_barrier();
  }

  // ---- epilogue: C/D layout col=lane&15, row=(lane>>4)*4+reg ----
  const int r4 = (lane >> 4) << 2;
#pragma unroll
  for (int j = 0; j < 4; ++j) {
    const int cn = bn * BN + wc * 64 + j * 16 + fr;
    const float aw = atwd[cn];
    const float zs = zpws[cn];
    const float bs = bias[cn];
#pragma unroll
    for (int mi = 0; mi < 8; ++mi) {
      const size_t rbase = (size_t)(bm * BM + wr * 128 + mi * 16 + r4) * (size_t)Nc;
#pragma unroll
      for (int r = 0; r < 4; ++r) {
        float v = (float)acc[mi][j][r] * aw - zs + bs;
        v = __half2float(__float2half(v));  // match fp16 output rounding
        out[rbase + (size_t)r * Nc + cn] = v;
      }
    }
  }
}

extern "C" void kernel_launch(void* const* d_in, const int* in_sizes, int n_in,
                              void* d_out, int out_size, void* d_ws, size_t ws_size,
                              hipStream_t stream) {
  const float* x         = (const float*)d_in[0];
  const float* act_delta = (const float*)d_in[1];
  const float* act_zp    = (const float*)d_in[2];
  const float* zpws      = (const float*)d_in[3];
  const float* atwd      = (const float*)d_in[4];
  const float* bias      = (const float*)d_in[5];
  const int*   w32       = (const int*)d_in[6];
  float* out = (float*)d_out;

  const int N = in_sizes[5];
  const int K = in_sizes[6] / N;
  const int M = in_sizes[0] / K;

  int8_t* q  = (int8_t*)d_ws;               // M*K bytes
  int8_t* wp = q + (size_t)M * K;           // N*K bytes

  {
    int n16 = (M * K) / 16;
    quant_x_kernel<<<(n16 + 255) / 256, 256, 0, stream>>>(x, act_delta, act_zp, q, n16);
  }
  {
    int n16 = (N * K) / 16;
    pack_w_kernel<<<(n16 + 255) / 256, 256, 0, stream>>>(w32, wp, n16);
  }
  {
    dim3 grid((M / BM) * (N / BN));
    gemm_i8_kernel<<<grid, THREADS, 0, stream>>>(q, wp, atwd, zpws, bias, out, M, N, K);
  }
}